// Round 1
// baseline (52.853 us; speedup 1.0000x reference)
//
#include <hip/hip_runtime.h>

#define NREL1 12   // NREL + 1 relation matrices
#define NN    128  // neighbours
#define EE    128  // in-features
#define FF    128  // out-features
#define BV    192  // B * V

// Pre-kernel: Wa1[r][e] = sum_f W[r,e,f] * a[f]; Wa2[r][e] = sum_f W[r,e,f] * a[F+f]
__global__ __launch_bounds__(128) void wa_kernel(const float* __restrict__ W,
                                                 const float* __restrict__ a,
                                                 float* __restrict__ wa) {
    int r = blockIdx.x;
    int e = threadIdx.x;
    const float* row = W + ((size_t)r * EE + e) * FF;
    float s1 = 0.f, s2 = 0.f;
#pragma unroll 4
    for (int f = 0; f < FF; ++f) {
        float w = row[f];
        s1 += w * a[f];
        s2 += w * a[FF + f];
    }
    wa[r * EE + e] = s1;
    wa[NREL1 * EE + r * EE + e] = s2;
}

__global__ __launch_bounds__(256) void gat_kernel(const float* __restrict__ fe,
                                                  const float* __restrict__ ne,
                                                  const int* __restrict__ widx,
                                                  const float* __restrict__ ind,
                                                  const float* __restrict__ W,
                                                  const float* __restrict__ wa,
                                                  float* __restrict__ out) {
    __shared__ float wa1[NREL1 * EE];
    __shared__ float wa2[NREL1 * EE];
    __shared__ float e_lds[NN];
    __shared__ float attn_lds[NN];
    __shared__ int   idx_lds[NN];
    __shared__ float s_lds[2][NREL1 * EE];
    __shared__ float out_part[FF];

    const int bv  = blockIdx.x;
    const int tid = threadIdx.x;
    const float* ne_bv = ne + (size_t)bv * NN * EE;
    const float* fe_bv = fe + (size_t)bv * NN * EE;

    // Stage Wa1/Wa2 + indices, zero relation accumulators
    for (int i = tid; i < NREL1 * EE; i += 256) {
        wa1[i] = wa[i];
        wa2[i] = wa[NREL1 * EE + i];
    }
    if (tid < NN) idx_lds[tid] = widx[bv * NN + tid];
    for (int i = tid; i < 2 * NREL1 * EE; i += 256) (&s_lds[0][0])[i] = 0.f;
    __syncthreads();

    const int wave = tid >> 6;
    const int lane = tid & 63;

    // Phase A: attention logits e[n] = leaky_relu(ne . Wa1[r] + fe . Wa2[r])
    for (int n = wave; n < NN; n += 4) {
        int r = idx_lds[n];
        const float2 nv = *(const float2*)(ne_bv + n * EE + lane * 2);
        const float2 fv = *(const float2*)(fe_bv + n * EE + lane * 2);
        const float* w1 = wa1 + r * EE;
        const float* w2 = wa2 + r * EE;
        float d = nv.x * w1[lane * 2] + nv.y * w1[lane * 2 + 1]
                + fv.x * w2[lane * 2] + fv.y * w2[lane * 2 + 1];
#pragma unroll
        for (int off = 32; off; off >>= 1) d += __shfl_xor(d, off);
        if (lane == 0) e_lds[n] = d > 0.f ? d : 0.2f * d;
    }
    __syncthreads();

    // Phase B: softmax over neighbours, then indicator mask (wave 0 only)
    if (wave == 0) {
        float v0 = e_lds[lane], v1 = e_lds[lane + 64];
        float m = fmaxf(v0, v1);
#pragma unroll
        for (int off = 32; off; off >>= 1) m = fmaxf(m, __shfl_xor(m, off));
        float ex0 = expf(v0 - m), ex1 = expf(v1 - m);
        float s = ex0 + ex1;
#pragma unroll
        for (int off = 32; off; off >>= 1) s += __shfl_xor(s, off);
        float inv = 1.f / s;
        attn_lds[lane]      = ex0 * inv * ind[bv * NN + lane];
        attn_lds[lane + 64] = ex1 * inv * ind[bv * NN + lane + 64];
    }
    __syncthreads();

    // Phase C: s[r][e] = sum_{n: idx[n]==r} attn[n] * ne[n][e]
    // Thread owns column e; two independent copies over n-halves (no races).
    {
        int h = tid >> 7;
        int e = tid & 127;
        float* sh = s_lds[h];
        for (int n = h; n < NN; n += 2) {
            float an = attn_lds[n];
            int r = idx_lds[n];
            sh[r * EE + e] += an * ne_bv[n * EE + e];
        }
    }
    __syncthreads();

    // Phase D: out[f] = sum_r sum_e s[r][e] * W[r][e][f]  (12 matvecs)
    {
        int f = tid & 127;
        int half = tid >> 7;
        float acc = 0.f;
        for (int r = half * 6; r < half * 6 + 6; ++r) {
            const float* Wr = W + (size_t)r * EE * FF;
            const float* s0 = &s_lds[0][r * EE];
            const float* s1 = &s_lds[1][r * EE];
#pragma unroll 4
            for (int e2 = 0; e2 < EE; ++e2) {
                acc += (s0[e2] + s1[e2]) * Wr[e2 * FF + f];
            }
        }
        if (half == 0) out_part[f] = acc;
        __syncthreads();
        if (half == 1) out[bv * FF + f] = out_part[f] + acc;
    }
}

extern "C" void kernel_launch(void* const* d_in, const int* in_sizes, int n_in,
                              void* d_out, int out_size, void* d_ws, size_t ws_size,
                              hipStream_t stream) {
    const float* fe  = (const float*)d_in[0];  // feature_embed  (B,V,N,E)
    const float* ne  = (const float*)d_in[1];  // neighbour_embed (B,V,N,E)
    const int*   wi  = (const int*)d_in[2];    // w_index (B,V,N)
    const float* ind = (const float*)d_in[3];  // indicator (B,V,N)
    const float* W   = (const float*)d_in[4];  // (12,E,F)
    const float* a   = (const float*)d_in[5];  // (2F,1)
    float* out = (float*)d_out;                // (B,V,F)
    float* wa  = (float*)d_ws;                 // 2 * 12 * 128 floats

    wa_kernel<<<NREL1, 128, 0, stream>>>(W, a, wa);
    gat_kernel<<<BV, 256, 0, stream>>>(fe, ne, wi, ind, W, wa, out);
}

// Round 2
// 52.396 us; speedup vs baseline: 1.0087x; 1.0087x over previous
//
#include <hip/hip_runtime.h>

#define NREL1 12   // NREL + 1 relation matrices
#define NN    128  // neighbours
#define EE    128  // in-features
#define FF    128  // out-features
#define BV    192  // B * V
#define NEDGE (BV * NN)      // 24576
#define RK    (NREL1 * EE)   // 1536 = flattened (r,e) K dim

// ws layout (in floats):
//   [0, 3072)            wa: Wa1[12][128] then Wa2[12][128]
//   [3072, 27648)        e_ws: logits per edge
//   [27648, 322560)      s_ws: S[bv][r*128+e]
#define WA_OFF 0
#define E_OFF  3072
#define S_OFF  27648

// K0: Wa1[r][e] = sum_f W[r,e,f]*a[f]; Wa2[r][e] = sum_f W[r,e,f]*a[F+f]
// wave per (r,e) row-dot, fully coalesced.
__global__ __launch_bounds__(256) void wa_kernel(const float* __restrict__ W,
                                                 const float* __restrict__ a,
                                                 float* __restrict__ wa) {
    int w    = blockIdx.x * 4 + (threadIdx.x >> 6);  // 1536 waves
    int lane = threadIdx.x & 63;
    int r = w >> 7, e = w & 127;
    const float* row = W + (size_t)(r * EE + e) * FF;
    float2 wv = *(const float2*)(row + lane * 2);
    float2 a1 = *(const float2*)(a + lane * 2);
    float2 a2 = *(const float2*)(a + FF + lane * 2);
    float d1 = wv.x * a1.x + wv.y * a1.y;
    float d2 = wv.x * a2.x + wv.y * a2.y;
#pragma unroll
    for (int off = 32; off; off >>= 1) {
        d1 += __shfl_xor(d1, off);
        d2 += __shfl_xor(d2, off);
    }
    if (lane == 0) {
        wa[r * EE + e]      = d1;
        wa[RK + r * EE + e] = d2;
    }
}

// K1: per-edge attention logit, wave per edge. The HBM-heavy kernel (25 MB).
__global__ __launch_bounds__(256) void logits_kernel(const float* __restrict__ fe,
                                                     const float* __restrict__ ne,
                                                     const int* __restrict__ widx,
                                                     const float* __restrict__ wa,
                                                     float* __restrict__ e_ws) {
    int edge = blockIdx.x * 4 + (threadIdx.x >> 6);  // 24576 edges
    int lane = threadIdx.x & 63;
    int r = widx[edge];
    const float2 nv = *(const float2*)(ne + (size_t)edge * EE + lane * 2);
    const float2 fv = *(const float2*)(fe + (size_t)edge * EE + lane * 2);
    const float2 w1 = *(const float2*)(wa + r * EE + lane * 2);
    const float2 w2 = *(const float2*)(wa + RK + r * EE + lane * 2);
    float d = nv.x * w1.x + nv.y * w1.y + fv.x * w2.x + fv.y * w2.y;
#pragma unroll
    for (int off = 32; off; off >>= 1) d += __shfl_xor(d, off);
    if (lane == 0) e_ws[edge] = d > 0.f ? d : 0.2f * d;
}

// K2: softmax + indicator mask + relation-bucketed aggregation
//     s_ws[bv][r*128+e] = sum_{n: idx[n]==r} attn[n]*ne[n][e]
// Also zero-inits out[bv][:] for K3's atomics.
__global__ __launch_bounds__(512) void agg_kernel(const float* __restrict__ ne,
                                                  const int* __restrict__ widx,
                                                  const float* __restrict__ ind,
                                                  const float* __restrict__ e_ws,
                                                  float* __restrict__ s_ws,
                                                  float* __restrict__ out) {
    __shared__ float attn[NN];
    __shared__ int   idx[NN];
    __shared__ float s[4][RK];

    const int bv  = blockIdx.x;
    const int tid = threadIdx.x;

    if (tid < NN) idx[tid] = widx[bv * NN + tid];
    if (tid < FF) out[bv * FF + tid] = 0.f;
    for (int i = tid; i < 4 * RK; i += 512) (&s[0][0])[i] = 0.f;

    if (tid < 64) {
        float v0 = e_ws[bv * NN + tid], v1 = e_ws[bv * NN + tid + 64];
        float m = fmaxf(v0, v1);
#pragma unroll
        for (int off = 32; off; off >>= 1) m = fmaxf(m, __shfl_xor(m, off));
        float ex0 = expf(v0 - m), ex1 = expf(v1 - m);
        float ssum = ex0 + ex1;
#pragma unroll
        for (int off = 32; off; off >>= 1) ssum += __shfl_xor(ssum, off);
        float inv = 1.f / ssum;
        attn[tid]      = ex0 * inv * ind[bv * NN + tid];
        attn[tid + 64] = ex1 * inv * ind[bv * NN + tid + 64];
    }
    __syncthreads();

    {
        const int q = tid >> 7;      // n-quarter: 4 independent accumulator copies
        const int e = tid & 127;     // owned column
        float* sq = s[q];
        const float* nb = ne + (size_t)bv * NN * EE;
        for (int n = q; n < NN; n += 4)
            sq[idx[n] * EE + e] += attn[n] * nb[n * EE + e];
    }
    __syncthreads();

    for (int i = tid; i < RK; i += 512)
        s_ws[(size_t)bv * RK + i] = s[0][i] + s[1][i] + s[2][i] + s[3][i];
}

// K3: out[bv][f] += S[bv][k] * Wflat[k][f], M=192 N=128 K=1536.
// grid (12 bv-tiles of 16) x (4 f-tiles of 32) x (4 K-splits of 384).
__global__ __launch_bounds__(256) void gemm_kernel(const float* __restrict__ s_ws,
                                                   const float* __restrict__ W,
                                                   float* __restrict__ out) {
    __shared__ float s_tile[16][128];
    __shared__ float w_tile[128][32];

    const int bv0 = blockIdx.x * 16;
    const int f0  = blockIdx.y * 32;
    const int tid = threadIdx.x;
    const int f_l = tid & 31;
    const int g   = tid >> 5;  // 0..7: owns bv rows g and g+8

    float acc0 = 0.f, acc1 = 0.f;

    for (int cc = 0; cc < 3; ++cc) {
        const int kbase = blockIdx.z * 384 + cc * 128;
        __syncthreads();  // protect previous iteration's LDS reads
        for (int i = tid; i < 16 * 128; i += 256) {
            int b = i >> 7, k = i & 127;
            s_tile[b][k] = s_ws[(size_t)(bv0 + b) * RK + kbase + k];
        }
        for (int i = tid; i < 128 * 32; i += 256) {
            int k = i >> 5, f = i & 31;
            w_tile[k][f] = W[(size_t)(kbase + k) * FF + f0 + f];
        }
        __syncthreads();
#pragma unroll 4
        for (int k = 0; k < 128; k += 4) {
            const float4 s0 = *(const float4*)&s_tile[g][k];
            const float4 s1 = *(const float4*)&s_tile[g + 8][k];
            const float w0 = w_tile[k][f_l], w1 = w_tile[k + 1][f_l];
            const float w2 = w_tile[k + 2][f_l], w3 = w_tile[k + 3][f_l];
            acc0 += s0.x * w0; acc0 += s0.y * w1; acc0 += s0.z * w2; acc0 += s0.w * w3;
            acc1 += s1.x * w0; acc1 += s1.y * w1; acc1 += s1.z * w2; acc1 += s1.w * w3;
        }
    }
    atomicAdd(&out[(size_t)(bv0 + g) * FF + f0 + f_l], acc0);
    atomicAdd(&out[(size_t)(bv0 + g + 8) * FF + f0 + f_l], acc1);
}

extern "C" void kernel_launch(void* const* d_in, const int* in_sizes, int n_in,
                              void* d_out, int out_size, void* d_ws, size_t ws_size,
                              hipStream_t stream) {
    const float* fe  = (const float*)d_in[0];  // feature_embed   (B,V,N,E)
    const float* ne  = (const float*)d_in[1];  // neighbour_embed (B,V,N,E)
    const int*   wi  = (const int*)d_in[2];    // w_index (B,V,N)
    const float* ind = (const float*)d_in[3];  // indicator (B,V,N)
    const float* W   = (const float*)d_in[4];  // (12,E,F)
    const float* a   = (const float*)d_in[5];  // (2F,1)
    float* out = (float*)d_out;                // (B,V,F)
    float* ws  = (float*)d_ws;

    float* wa   = ws + WA_OFF;
    float* e_ws = ws + E_OFF;
    float* s_ws = ws + S_OFF;

    wa_kernel<<<RK / 4, 256, 0, stream>>>(W, a, wa);
    logits_kernel<<<NEDGE / 4, 256, 0, stream>>>(fe, ne, wi, wa, e_ws);
    agg_kernel<<<BV, 512, 0, stream>>>(ne, wi, ind, e_ws, s_ws, out);
    gemm_kernel<<<dim3(12, 4, 4), 256, 0, stream>>>(s_ws, W, out);
}

// Round 3
// 40.819 us; speedup vs baseline: 1.2948x; 1.2836x over previous
//
#include <hip/hip_runtime.h>

#define NREL1 12   // NREL + 1 relation matrices
#define NN    128  // neighbours
#define EE    128  // in-features
#define FF    128  // out-features
#define BV    192  // B * V
#define RK    (NREL1 * EE)   // 1536

// One fused kernel: block per (b,v), 1024 threads (16 waves).
// Phase 0: Wa1/Wa2 = W @ a1, W @ a2   (redundant per block; W is L2-resident)
// Phase A: per-edge logits            (wave per edge, 8 edges/wave)
// Phase B: softmax + indicator mask   (wave 0)
// Phase C: relation-bucketed scatter  (8 LDS accumulator copies, race-free)
// Phase D: out = S @ W                (8-way K-split, coalesced W reads)
__global__ __launch_bounds__(1024) void gat_fused(const float* __restrict__ fe,
                                                  const float* __restrict__ ne,
                                                  const int* __restrict__ widx,
                                                  const float* __restrict__ ind,
                                                  const float* __restrict__ W,
                                                  const float* __restrict__ a,
                                                  float* __restrict__ out) {
    __shared__ float a_lds[2 * FF];     // 1 KB
    __shared__ float wa1[RK];           // 6 KB
    __shared__ float wa2[RK];           // 6 KB
    __shared__ float e_lds[NN];
    __shared__ float attn[NN];
    __shared__ int   idx[NN];
    __shared__ float s[8][RK];          // 48 KB
    __shared__ float red[8][FF];        // 4 KB

    const int bv   = blockIdx.x;
    const int tid  = threadIdx.x;
    const int wave = tid >> 6;
    const int lane = tid & 63;

    if (tid < 2 * FF) a_lds[tid] = a[tid];
    if (tid < NN)     idx[tid]   = widx[bv * NN + tid];
    for (int i = tid; i < 8 * RK; i += 1024) (&s[0][0])[i] = 0.f;
    __syncthreads();

    // ---- Phase 0: wa1[i] = W_row(i) . a1, wa2[i] = W_row(i) . a2 ----
    for (int i = tid; i < RK; i += 1024) {
        const float4* row = (const float4*)(W + (size_t)i * FF);
        const float4* a1  = (const float4*)a_lds;
        const float4* a2  = (const float4*)(a_lds + FF);
        float d1 = 0.f, d2 = 0.f;
#pragma unroll 8
        for (int f4 = 0; f4 < FF / 4; ++f4) {
            float4 w = row[f4];
            float4 x = a1[f4];
            float4 y = a2[f4];
            d1 += w.x * x.x + w.y * x.y + w.z * x.z + w.w * x.w;
            d2 += w.x * y.x + w.y * y.y + w.z * y.z + w.w * y.w;
        }
        wa1[i] = d1;
        wa2[i] = d2;
    }
    __syncthreads();

    // ---- Phase A: logits, wave per edge ----
    const float* ne_bv = ne + (size_t)bv * NN * EE;
    const float* fe_bv = fe + (size_t)bv * NN * EE;
    for (int n = wave; n < NN; n += 16) {
        int r = idx[n];
        const float2 nv = *(const float2*)(ne_bv + n * EE + lane * 2);
        const float2 fv = *(const float2*)(fe_bv + n * EE + lane * 2);
        const float2 w1 = *(const float2*)(wa1 + r * EE + lane * 2);
        const float2 w2 = *(const float2*)(wa2 + r * EE + lane * 2);
        float d = nv.x * w1.x + nv.y * w1.y + fv.x * w2.x + fv.y * w2.y;
#pragma unroll
        for (int off = 32; off; off >>= 1) d += __shfl_xor(d, off);
        if (lane == 0) e_lds[n] = d > 0.f ? d : 0.2f * d;
    }
    __syncthreads();

    // ---- Phase B: softmax over neighbours + indicator mask (wave 0) ----
    if (tid < 64) {
        float v0 = e_lds[tid], v1 = e_lds[tid + 64];
        float m = fmaxf(v0, v1);
#pragma unroll
        for (int off = 32; off; off >>= 1) m = fmaxf(m, __shfl_xor(m, off));
        float ex0 = expf(v0 - m), ex1 = expf(v1 - m);
        float ssum = ex0 + ex1;
#pragma unroll
        for (int off = 32; off; off >>= 1) ssum += __shfl_xor(ssum, off);
        float inv = 1.f / ssum;
        attn[tid]      = ex0 * inv * ind[bv * NN + tid];
        attn[tid + 64] = ex1 * inv * ind[bv * NN + tid + 64];
    }
    __syncthreads();

    // ---- Phase C: s[r][e] += attn[n] * ne[n][e], 8 independent copies ----
    {
        const int c = tid >> 7;     // copy 0..7
        const int e = tid & 127;    // owned column
        float* sc = s[c];
        for (int n = c; n < NN; n += 8)
            sc[idx[n] * EE + e] += attn[n] * ne_bv[n * EE + e];
    }
    __syncthreads();

    // reduce the 8 copies into s[0]
    for (int k = tid; k < RK; k += 1024) {
        float v = s[0][k] + s[1][k] + s[2][k] + s[3][k]
                + s[4][k] + s[5][k] + s[6][k] + s[7][k];
        s[0][k] = v;
    }
    __syncthreads();

    // ---- Phase D: out[f] = sum_k s[0][k] * W[k][f], 8-way K-split ----
    {
        const int f  = tid & 127;
        const int kg = tid >> 7;    // K group 0..7, 192 k's each
        float acc = 0.f;
        const float* Wp = W + f;
#pragma unroll 8
        for (int j = 0; j < RK / 8; ++j) {
            int k = kg * (RK / 8) + j;
            acc += s[0][k] * Wp[(size_t)k * FF];
        }
        red[kg][f] = acc;
    }
    __syncthreads();
    if (tid < FF) {
        float o = red[0][tid] + red[1][tid] + red[2][tid] + red[3][tid]
                + red[4][tid] + red[5][tid] + red[6][tid] + red[7][tid];
        out[bv * FF + tid] = o;
    }
}

extern "C" void kernel_launch(void* const* d_in, const int* in_sizes, int n_in,
                              void* d_out, int out_size, void* d_ws, size_t ws_size,
                              hipStream_t stream) {
    const float* fe  = (const float*)d_in[0];  // feature_embed   (B,V,N,E)
    const float* ne  = (const float*)d_in[1];  // neighbour_embed (B,V,N,E)
    const int*   wi  = (const int*)d_in[2];    // w_index (B,V,N)
    const float* ind = (const float*)d_in[3];  // indicator (B,V,N)
    const float* W   = (const float*)d_in[4];  // (12,E,F)
    const float* a   = (const float*)d_in[5];  // (2F,1)
    float* out = (float*)d_out;                // (B,V,F)

    gat_fused<<<BV, 1024, 0, stream>>>(fe, ne, wi, ind, W, a, out);
}